// Round 5
// baseline (484.897 us; speedup 1.0000x reference)
//
#include <hip/hip_runtime.h>

// ---------------------------------------------------------------------------
// GCN 2-layer, CSR-gather formulation. R5:
//  - line-exclusive (64B-strided) cnt/cursor counters: no cross-node cache-line
//    sharing on the atomic paths (R4 evidence: 47B HBM write-through/atomic)
//  - hist un-fused from gemm1 (R4 fusion capped hist occupancy at 28% via LDS)
// ---------------------------------------------------------------------------

#define SCAN_BS 256
#define SCAN_ITEMS 4
#define SCAN_CHUNK (SCAN_BS * SCAN_ITEMS)  // 1024
#define CSTR 16  // counter stride in ints (64B line-exclusive)

__global__ void k_hist(const int* __restrict__ dst, int* __restrict__ cnt, int E) {
    int e = blockIdx.x * blockDim.x + threadIdx.x;
    if (e < E) atomicAdd(&cnt[dst[e] * CSTR], 1);
}

// h[n][64] = x[n][128] @ W[128][64]; W fully LDS-resident, 16 nodes/block
__global__ __launch_bounds__(256) void k_gemm1(const float* __restrict__ x,
                                               const float* __restrict__ W,
                                               float* __restrict__ h, int n) {
    __shared__ float Ws[128 * 64];
    __shared__ float xs[16][128];
    const int t = threadIdx.x;
    for (int i = t; i < 128 * 64; i += 256) Ws[i] = W[i];
    const int node0 = blockIdx.x * 16;
    for (int i = t; i < 16 * 128; i += 256) {
        int nn = i >> 7, kk = i & 127;
        int node = node0 + nn;
        xs[nn][kk] = (node < n) ? x[(size_t)node * 128 + kk] : 0.0f;
    }
    __syncthreads();
    const int f = t & 63;
    const int ng = t >> 6;  // 0..3; whole wave shares ng -> xs reads broadcast
    float a0 = 0.f, a1 = 0.f, a2 = 0.f, a3 = 0.f;
#pragma unroll 4
    for (int k = 0; k < 128; ++k) {
        float wv = Ws[k * 64 + f];
        a0 = fmaf(xs[ng][k], wv, a0);
        a1 = fmaf(xs[ng + 4][k], wv, a1);
        a2 = fmaf(xs[ng + 8][k], wv, a2);
        a3 = fmaf(xs[ng + 12][k], wv, a3);
    }
    if (node0 + ng < n)      h[(size_t)(node0 + ng) * 64 + f] = a0;
    if (node0 + ng + 4 < n)  h[(size_t)(node0 + ng + 4) * 64 + f] = a1;
    if (node0 + ng + 8 < n)  h[(size_t)(node0 + ng + 8) * 64 + f] = a2;
    if (node0 + ng + 12 < n) h[(size_t)(node0 + ng + 12) * 64 + f] = a3;
}

// ---- 3-phase scan over strided cnt[CSTR*i] -> rowptr[n+1] + cursor[CSTR*i] ----
__global__ __launch_bounds__(SCAN_BS) void k_scanA(const int* __restrict__ cnt,
                                                   int* __restrict__ bsum, int n) {
    __shared__ int red[SCAN_BS];
    const int b = blockIdx.x, t = threadIdx.x;
    const int base = b * SCAN_CHUNK + t * SCAN_ITEMS;
    int s = 0;
#pragma unroll
    for (int j = 0; j < SCAN_ITEMS; ++j) {
        int i = base + j;
        if (i < n) s += cnt[i * CSTR];
    }
    red[t] = s;
    __syncthreads();
    for (int off = SCAN_BS / 2; off > 0; off >>= 1) {
        if (t < off) red[t] += red[t + off];
        __syncthreads();
    }
    if (t == 0) bsum[b] = red[0];
}

__global__ __launch_bounds__(128) void k_scanB(const int* __restrict__ bsum,
                                               int* __restrict__ boff,
                                               int* __restrict__ rowptr, int nb, int n) {
    __shared__ int lds[128];
    const int t = threadIdx.x;
    int carry = 0;
    for (int base = 0; base < nb; base += 128) {
        int idx = base + t;
        int v = (idx < nb) ? bsum[idx] : 0;
        lds[t] = v;
        __syncthreads();
        for (int off = 1; off < 128; off <<= 1) {
            int u = (t >= off) ? lds[t - off] : 0;
            __syncthreads();
            lds[t] += u;
            __syncthreads();
        }
        if (idx < nb) boff[idx] = lds[t] - v + carry;
        carry += lds[127];
        __syncthreads();
    }
    if (t == 0) rowptr[n] = carry;
}

__global__ __launch_bounds__(SCAN_BS) void k_scanC(const int* __restrict__ cnt,
                                                   const int* __restrict__ boff,
                                                   int* __restrict__ rowptr,
                                                   int* __restrict__ cursor, int n) {
    __shared__ int lds[SCAN_BS];
    const int b = blockIdx.x, t = threadIdx.x;
    const int base = b * SCAN_CHUNK + t * SCAN_ITEMS;
    int v[SCAN_ITEMS];
    int s = 0;
#pragma unroll
    for (int j = 0; j < SCAN_ITEMS; ++j) {
        int i = base + j;
        v[j] = (i < n) ? cnt[i * CSTR] : 0;
        s += v[j];
    }
    lds[t] = s;
    __syncthreads();
    for (int off = 1; off < SCAN_BS; off <<= 1) {
        int u = (t >= off) ? lds[t - off] : 0;
        __syncthreads();
        lds[t] += u;
        __syncthreads();
    }
    int excl = lds[t] - s + boff[b];
#pragma unroll
    for (int j = 0; j < SCAN_ITEMS; ++j) {
        int i = base + j;
        if (i < n) {
            rowptr[i] = excl;
            cursor[i * CSTR] = excl;
            excl += v[j];
        }
    }
}

// Bucket edges by dst: epack[p] = {src, bitcast(ew)} — single 8B store.
__global__ void k_build(const int* __restrict__ src, const int* __restrict__ dst,
                        const float* __restrict__ ew, int* __restrict__ cursor,
                        int2* __restrict__ epack, int E) {
    int e = blockIdx.x * blockDim.x + threadIdx.x;
    if (e >= E) return;
    int d = dst[e];
    int p = atomicAdd(&cursor[d * CSTR], 1);
    int2 pk;
    pk.x = src[e];
    pk.y = __float_as_int(ew[e]);
    epack[p] = pk;
}

// dinv[i] = rsqrt(1 + sum of ew over row i).
__global__ void k_dinv(const int* __restrict__ rowptr, const int2* __restrict__ ep,
                       float* __restrict__ dinv, int n) {
    int i = blockIdx.x * blockDim.x + threadIdx.x;
    if (i >= n) return;
    int lo = rowptr[i], hi = rowptr[i + 1];
    float s = 1.0f;  // self loop
    for (int e = lo; e < hi; ++e) s += __int_as_float(ep[e].y);
    dinv[i] = rsqrtf(s);
}

// Gather-aggregate, F=64: one wave per node, lane = feature.
__global__ __launch_bounds__(256) void k_agg64(const float* __restrict__ h,
                                               const int* __restrict__ rowptr,
                                               const int2* __restrict__ ep,
                                               const float* __restrict__ dinv,
                                               float* __restrict__ agg, int n) {
    const int node = (blockIdx.x * 256 + threadIdx.x) >> 6;
    const int lane = threadIdx.x & 63;
    if (node >= n) return;
    const float di = dinv[node];
    float accE = 0.f;
    const int lo = rowptr[node], hi = rowptr[node + 1];
    int i = lo;
    for (; i + 3 < hi; i += 4) {
        int2 p0 = ep[i], p1 = ep[i + 1], p2 = ep[i + 2], p3 = ep[i + 3];
        float w0 = dinv[p0.x] * __int_as_float(p0.y);
        float w1 = dinv[p1.x] * __int_as_float(p1.y);
        float w2 = dinv[p2.x] * __int_as_float(p2.y);
        float w3 = dinv[p3.x] * __int_as_float(p3.y);
        float v0 = h[(size_t)p0.x * 64 + lane];
        float v1 = h[(size_t)p1.x * 64 + lane];
        float v2 = h[(size_t)p2.x * 64 + lane];
        float v3 = h[(size_t)p3.x * 64 + lane];
        accE = fmaf(v0, w0, accE);
        accE = fmaf(v1, w1, accE);
        accE = fmaf(v2, w2, accE);
        accE = fmaf(v3, w3, accE);
    }
    for (; i < hi; ++i) {
        int2 p = ep[i];
        accE = fmaf(h[(size_t)p.x * 64 + lane], dinv[p.x] * __int_as_float(p.y), accE);
    }
    float self = h[(size_t)node * 64 + lane];
    agg[(size_t)node * 64 + lane] = (fmaf(self, di, accE)) * di;
}

// Gather-aggregate, F=16: one 16-lane group per node.
__global__ __launch_bounds__(256) void k_agg16(const float* __restrict__ h,
                                               const int* __restrict__ rowptr,
                                               const int2* __restrict__ ep,
                                               const float* __restrict__ dinv,
                                               float* __restrict__ agg, int n) {
    const int node = (blockIdx.x * 256 + threadIdx.x) >> 4;
    const int lane = threadIdx.x & 15;
    if (node >= n) return;
    const float di = dinv[node];
    float accE = 0.f;
    const int lo = rowptr[node], hi = rowptr[node + 1];
    int i = lo;
    for (; i + 3 < hi; i += 4) {
        int2 p0 = ep[i], p1 = ep[i + 1], p2 = ep[i + 2], p3 = ep[i + 3];
        float w0 = dinv[p0.x] * __int_as_float(p0.y);
        float w1 = dinv[p1.x] * __int_as_float(p1.y);
        float w2 = dinv[p2.x] * __int_as_float(p2.y);
        float w3 = dinv[p3.x] * __int_as_float(p3.y);
        float v0 = h[(size_t)p0.x * 16 + lane];
        float v1 = h[(size_t)p1.x * 16 + lane];
        float v2 = h[(size_t)p2.x * 16 + lane];
        float v3 = h[(size_t)p3.x * 16 + lane];
        accE = fmaf(v0, w0, accE);
        accE = fmaf(v1, w1, accE);
        accE = fmaf(v2, w2, accE);
        accE = fmaf(v3, w3, accE);
    }
    for (; i < hi; ++i) {
        int2 p = ep[i];
        accE = fmaf(h[(size_t)p.x * 16 + lane], dinv[p.x] * __int_as_float(p.y), accE);
    }
    float self = h[(size_t)node * 16 + lane];
    agg[(size_t)node * 16 + lane] = (fmaf(self, di, accE)) * di;
}

// h2[n][16] = relu(a[n][64] + b1) @ W[64][16]; bias+relu fused into LDS load.
__global__ __launch_bounds__(256) void k_gemm2(const float* __restrict__ a,
                                               const float* __restrict__ W,
                                               const float* __restrict__ b1,
                                               float* __restrict__ h2, int n) {
    __shared__ float Ws[64 * 16];
    __shared__ float xs[32][68];
    const int t = threadIdx.x;
    for (int i = t; i < 64 * 16; i += 256) Ws[i] = W[i];
    const int node0 = blockIdx.x * 32;
    for (int i = t; i < 32 * 64; i += 256) {
        int nn = i >> 6, kk = i & 63;
        int node = node0 + nn;
        xs[nn][kk] = (node < n) ? fmaxf(a[(size_t)node * 64 + kk] + b1[kk], 0.0f) : 0.0f;
    }
    __syncthreads();
    const int f = t & 15;
    const int ng = t >> 4;  // 0..15
    float a0 = 0.f, a1 = 0.f;
#pragma unroll 4
    for (int k = 0; k < 64; ++k) {
        float wv = Ws[k * 16 + f];
        a0 = fmaf(xs[ng][k], wv, a0);
        a1 = fmaf(xs[ng + 16][k], wv, a1);
    }
    if (node0 + ng < n)      h2[(size_t)(node0 + ng) * 16 + f] = a0;
    if (node0 + ng + 16 < n) h2[(size_t)(node0 + ng + 16) * 16 + f] = a1;
}

// In-place: out[i][:] = log_softmax(out[i][:] + b2)
__global__ void k_logsoftmax(float* __restrict__ out, const float* __restrict__ b2, int n) {
    int i = blockIdx.x * blockDim.x + threadIdx.x;
    if (i >= n) return;
    const size_t base = (size_t)i * 16;
    float v[16];
#pragma unroll
    for (int f = 0; f < 16; ++f) v[f] = out[base + f] + b2[f];
    float m = v[0];
#pragma unroll
    for (int f = 1; f < 16; ++f) m = fmaxf(m, v[f]);
    float s = 0.f;
#pragma unroll
    for (int f = 0; f < 16; ++f) s += __expf(v[f] - m);
    float lse = __logf(s);
#pragma unroll
    for (int f = 0; f < 16; ++f) out[base + f] = v[f] - m - lse;
}

extern "C" void kernel_launch(void* const* d_in, const int* in_sizes, int n_in,
                              void* d_out, int out_size, void* d_ws, size_t ws_size,
                              hipStream_t stream) {
    const float* x  = (const float*)d_in[0];
    const int*   ei = (const int*)d_in[1];   // [2, E]
    const float* ew = (const float*)d_in[2];
    const float* W1 = (const float*)d_in[3];
    const float* b1 = (const float*)d_in[4];
    const float* W2 = (const float*)d_in[5];
    const float* b2 = (const float*)d_in[6];
    float* out = (float*)d_out;

    const int n = in_sizes[0] / 128;  // 100000
    const int E = in_sizes[2];        // 1600000
    const int* srcv = ei;
    const int* dstv = ei + E;

    // Workspace (4B units). cnt/cursor (line-strided) alias agg1's region
    // (dead until k_agg64; cursor is last used by k_build which precedes it).
    float* wsf = (float*)d_ws;
    size_t off = 0;
    float* dinv = wsf + off; off += n;
    float* h1   = wsf + off; off += (size_t)n * 64;   // reused as h2[n*16]
    float* agg1 = wsf + off; off += (size_t)n * 64;
    off = (off + 1) & ~(size_t)1;                     // 8B align
    int2* epack = (int2*)(wsf + off); off += (size_t)E * 2;
    int* rowptr = (int*)(wsf + off); off += n + 1;
    int* bsum   = (int*)(wsf + off); off += 1024;
    int* boff   = (int*)(wsf + off); off += 1024;
    int* cnt    = (int*)agg1;                       // [CSTR*n]
    int* cursor = (int*)agg1 + (size_t)CSTR * n;    // [CSTR*n]

    const int TB = 256;
    const int NBs = (n + SCAN_CHUNK - 1) / SCAN_CHUNK;

    // histogram (line-exclusive counters), gemm1 independent alongside
    hipMemsetAsync(cnt, 0, (size_t)CSTR * n * sizeof(int), stream);
    k_hist<<<(E + TB - 1) / TB, TB, 0, stream>>>(dstv, cnt, E);
    k_gemm1<<<(n + 15) / 16, TB, 0, stream>>>(x, W1, h1, n);

    // CSR build
    k_scanA<<<NBs, SCAN_BS, 0, stream>>>(cnt, bsum, n);
    k_scanB<<<1, 128, 0, stream>>>(bsum, boff, rowptr, NBs, n);
    k_scanC<<<NBs, SCAN_BS, 0, stream>>>(cnt, boff, rowptr, cursor, n);
    k_build<<<(E + TB - 1) / TB, TB, 0, stream>>>(srcv, dstv, ew, cursor, epack, E);

    // weighted degree -> dinv (coalesced segmented sum, no atomics)
    k_dinv<<<(n + TB - 1) / TB, TB, 0, stream>>>(rowptr, epack, dinv, n);

    // layer 1 aggregation
    k_agg64<<<(n * 64 + TB - 1) / TB, TB, 0, stream>>>(h1, rowptr, epack, dinv, agg1, n);

    // layer 2 (h2 reuses h1 buffer)
    k_gemm2<<<(n + 31) / 32, TB, 0, stream>>>(agg1, W2, b1, h1, n);
    k_agg16<<<(n * 16 + TB - 1) / TB, TB, 0, stream>>>(h1, rowptr, epack, dinv, out, n);

    // epilogue
    k_logsoftmax<<<(n + TB - 1) / TB, TB, 0, stream>>>(out, b2, n);
}

// Round 6
// 418.311 us; speedup vs baseline: 1.1592x; 1.1592x over previous
//
#include <hip/hip_runtime.h>

// ---------------------------------------------------------------------------
// GCN 2-layer, CSR-gather. R6:
//  - two-level bucketed counting sort for CSR build (R5 evidence: one-shot
//    scatter = 64B HBM write-through per 8B store; bucket-append streams
//    coalesce in L2). Buckets = dst>>7 (128 nodes each).
//  - k_p2 finalizes CSR per bucket in LDS and emits rowptr + dinv (replaces
//    k_hist/k_scan*/k_build/k_dinv).
//  - dinv prescaled into gemm outputs (h1s/h2s) -> agg kernels have no
//    per-edge dinv gather: agg = di*(sum h_s[src]*ew + h_s[self]).
// ---------------------------------------------------------------------------

#define BSHIFT 7
#define BNODES 128             // nodes per bucket
#define NBUK_MAX 1024          // requires n <= 131072 (n = 100000 here)
#define CSTR 16                // counter stride (64B line-exclusive)

// Pass 0: LDS-privatized bucket histogram. 8192 edges per block.
__global__ __launch_bounds__(256) void k_p0(const int* __restrict__ dst,
                                            int* __restrict__ bcnt, int E, int nbuk) {
    __shared__ int lcnt[NBUK_MAX];
    for (int j = threadIdx.x; j < nbuk; j += 256) lcnt[j] = 0;
    __syncthreads();
    int base = blockIdx.x * 8192;
    int end = min(base + 8192, E);
    for (int i = base + threadIdx.x; i < end; i += 256)
        atomicAdd(&lcnt[dst[i] >> BSHIFT], 1);
    __syncthreads();
    for (int j = threadIdx.x; j < nbuk; j += 256) {
        int v = lcnt[j];
        if (v) atomicAdd(&bcnt[j * CSTR], v);
    }
}

// Scan bucket counts -> boff[nbuk+1] (dense) + bcur (strided cursors).
__global__ __launch_bounds__(1024) void k_pscan(const int* __restrict__ bcnt,
                                                int* __restrict__ boff,
                                                int* __restrict__ bcur, int nbuk) {
    __shared__ int lds[1024];
    const int t = threadIdx.x;
    int v = (t < nbuk) ? bcnt[t * CSTR] : 0;
    lds[t] = v;
    __syncthreads();
    for (int off = 1; off < 1024; off <<= 1) {
        int u = (t >= off) ? lds[t - off] : 0;
        __syncthreads();
        lds[t] += u;
        __syncthreads();
    }
    int excl = lds[t] - v;
    if (t < nbuk) { boff[t] = excl; bcur[t * CSTR] = excl; }
    if (t == nbuk - 1) boff[nbuk] = lds[t];
}

// Pass 1: append {src | dlo<<17, ew} to the dst bucket. 782 sequential
// write streams -> L2-coalesced full-line writebacks.
__global__ void k_p1(const int* __restrict__ src, const int* __restrict__ dst,
                     const float* __restrict__ ew, int* __restrict__ bcur,
                     int2* __restrict__ tmp, int E) {
    int e = blockIdx.x * blockDim.x + threadIdx.x;
    if (e >= E) return;
    int d = dst[e];
    int p = atomicAdd(&bcur[(d >> BSHIFT) * CSTR], 1);
    int2 pk;
    pk.x = src[e] | ((d & (BNODES - 1)) << 17);
    pk.y = __float_as_int(ew[e]);
    tmp[p] = pk;
}

// Pass 2: one block per bucket. Local hist+scan -> exact CSR order (scatter
// confined to a ~16KB window), rowptr, and dinv (weighted degree incl self).
__global__ __launch_bounds__(256) void k_p2(const int2* __restrict__ tmp,
                                            const int* __restrict__ boff,
                                            int* __restrict__ rowptr,
                                            int2* __restrict__ epack,
                                            float* __restrict__ dinv,
                                            int n, int nbuk) {
    __shared__ int cnt[BNODES];
    __shared__ int pos[BNODES];
    __shared__ float degf[BNODES];
    const int b = blockIdx.x, t = threadIdx.x;
    const int node0 = b << BSHIFT;
    if (t < BNODES) { cnt[t] = 0; degf[t] = 0.f; }
    __syncthreads();
    const int lo = boff[b], hi = boff[b + 1];
    for (int i = lo + t; i < hi; i += 256) {
        int2 pk = tmp[i];
        int dlo = (pk.x >> 17) & (BNODES - 1);
        atomicAdd(&cnt[dlo], 1);
        atomicAdd(&degf[dlo], __int_as_float(pk.y));
    }
    __syncthreads();
    // inclusive scan of cnt into pos (threads 0..127 active, all sync)
    int own = (t < BNODES) ? cnt[t] : 0;
    if (t < BNODES) pos[t] = own;
    __syncthreads();
    for (int off = 1; off < BNODES; off <<= 1) {
        int u = (t < BNODES && t >= off) ? pos[t - off] : 0;
        __syncthreads();
        if (t < BNODES) pos[t] += u;
        __syncthreads();
    }
    if (t < BNODES) {
        int excl = pos[t] - own;
        int node = node0 + t;
        if (node < n) {
            rowptr[node] = lo + excl;
            dinv[node] = rsqrtf(1.0f + degf[t]);
        }
        pos[t] = excl;  // becomes the local cursor
    }
    if (b == nbuk - 1 && t == 0) rowptr[n] = hi;
    __syncthreads();
    for (int i = lo + t; i < hi; i += 256) {
        int2 pk = tmp[i];
        int dlo = (pk.x >> 17) & (BNODES - 1);
        int p = lo + atomicAdd(&pos[dlo], 1);
        int2 o;
        o.x = pk.x & 0x1FFFF;
        o.y = pk.y;
        epack[p] = o;
    }
}

// h1s[n][64] = (x[n][128] @ W[128][64]) * dinv[node]
__global__ __launch_bounds__(256) void k_gemm1(const float* __restrict__ x,
                                               const float* __restrict__ W,
                                               const float* __restrict__ dinv,
                                               float* __restrict__ h, int n) {
    __shared__ float Ws[128 * 64];
    __shared__ float xs[16][128];
    const int t = threadIdx.x;
    for (int i = t; i < 128 * 64; i += 256) Ws[i] = W[i];
    const int node0 = blockIdx.x * 16;
    for (int i = t; i < 16 * 128; i += 256) {
        int nn = i >> 7, kk = i & 127;
        int node = node0 + nn;
        xs[nn][kk] = (node < n) ? x[(size_t)node * 128 + kk] : 0.0f;
    }
    __syncthreads();
    const int f = t & 63;
    const int ng = t >> 6;  // 0..3; whole wave shares ng -> xs reads broadcast
    float a0 = 0.f, a1 = 0.f, a2 = 0.f, a3 = 0.f;
#pragma unroll 4
    for (int k = 0; k < 128; ++k) {
        float wv = Ws[k * 64 + f];
        a0 = fmaf(xs[ng][k], wv, a0);
        a1 = fmaf(xs[ng + 4][k], wv, a1);
        a2 = fmaf(xs[ng + 8][k], wv, a2);
        a3 = fmaf(xs[ng + 12][k], wv, a3);
    }
    if (node0 + ng < n)      h[(size_t)(node0 + ng) * 64 + f]      = a0 * dinv[node0 + ng];
    if (node0 + ng + 4 < n)  h[(size_t)(node0 + ng + 4) * 64 + f]  = a1 * dinv[node0 + ng + 4];
    if (node0 + ng + 8 < n)  h[(size_t)(node0 + ng + 8) * 64 + f]  = a2 * dinv[node0 + ng + 8];
    if (node0 + ng + 12 < n) h[(size_t)(node0 + ng + 12) * 64 + f] = a3 * dinv[node0 + ng + 12];
}

// Gather-aggregate, F=64: agg = di * (sum_e h[src]*ew + h[self])
__global__ __launch_bounds__(256) void k_agg64(const float* __restrict__ h,
                                               const int* __restrict__ rowptr,
                                               const int2* __restrict__ ep,
                                               const float* __restrict__ dinv,
                                               float* __restrict__ agg, int n) {
    const int node = (blockIdx.x * 256 + threadIdx.x) >> 6;
    const int lane = threadIdx.x & 63;
    if (node >= n) return;
    const float di = dinv[node];
    float accE = 0.f;
    const int lo = rowptr[node], hi = rowptr[node + 1];
    int i = lo;
    for (; i + 3 < hi; i += 4) {
        int2 p0 = ep[i], p1 = ep[i + 1], p2 = ep[i + 2], p3 = ep[i + 3];
        float v0 = h[(size_t)p0.x * 64 + lane];
        float v1 = h[(size_t)p1.x * 64 + lane];
        float v2 = h[(size_t)p2.x * 64 + lane];
        float v3 = h[(size_t)p3.x * 64 + lane];
        accE = fmaf(v0, __int_as_float(p0.y), accE);
        accE = fmaf(v1, __int_as_float(p1.y), accE);
        accE = fmaf(v2, __int_as_float(p2.y), accE);
        accE = fmaf(v3, __int_as_float(p3.y), accE);
    }
    for (; i < hi; ++i) {
        int2 p = ep[i];
        accE = fmaf(h[(size_t)p.x * 64 + lane], __int_as_float(p.y), accE);
    }
    float self = h[(size_t)node * 64 + lane];
    agg[(size_t)node * 64 + lane] = di * (accE + self);
}

// Gather-aggregate, F=16: same identity.
__global__ __launch_bounds__(256) void k_agg16(const float* __restrict__ h,
                                               const int* __restrict__ rowptr,
                                               const int2* __restrict__ ep,
                                               const float* __restrict__ dinv,
                                               float* __restrict__ agg, int n) {
    const int node = (blockIdx.x * 256 + threadIdx.x) >> 4;
    const int lane = threadIdx.x & 15;
    if (node >= n) return;
    const float di = dinv[node];
    float accE = 0.f;
    const int lo = rowptr[node], hi = rowptr[node + 1];
    int i = lo;
    for (; i + 3 < hi; i += 4) {
        int2 p0 = ep[i], p1 = ep[i + 1], p2 = ep[i + 2], p3 = ep[i + 3];
        float v0 = h[(size_t)p0.x * 16 + lane];
        float v1 = h[(size_t)p1.x * 16 + lane];
        float v2 = h[(size_t)p2.x * 16 + lane];
        float v3 = h[(size_t)p3.x * 16 + lane];
        accE = fmaf(v0, __int_as_float(p0.y), accE);
        accE = fmaf(v1, __int_as_float(p1.y), accE);
        accE = fmaf(v2, __int_as_float(p2.y), accE);
        accE = fmaf(v3, __int_as_float(p3.y), accE);
    }
    for (; i < hi; ++i) {
        int2 p = ep[i];
        accE = fmaf(h[(size_t)p.x * 16 + lane], __int_as_float(p.y), accE);
    }
    float self = h[(size_t)node * 16 + lane];
    agg[(size_t)node * 16 + lane] = di * (accE + self);
}

// h2s[n][16] = (relu(a[n][64] + b1) @ W[64][16]) * dinv[node]
__global__ __launch_bounds__(256) void k_gemm2(const float* __restrict__ a,
                                               const float* __restrict__ W,
                                               const float* __restrict__ b1,
                                               const float* __restrict__ dinv,
                                               float* __restrict__ h2, int n) {
    __shared__ float Ws[64 * 16];
    __shared__ float xs[32][68];
    const int t = threadIdx.x;
    for (int i = t; i < 64 * 16; i += 256) Ws[i] = W[i];
    const int node0 = blockIdx.x * 32;
    for (int i = t; i < 32 * 64; i += 256) {
        int nn = i >> 6, kk = i & 63;
        int node = node0 + nn;
        xs[nn][kk] = (node < n) ? fmaxf(a[(size_t)node * 64 + kk] + b1[kk], 0.0f) : 0.0f;
    }
    __syncthreads();
    const int f = t & 15;
    const int ng = t >> 4;  // 0..15
    float a0 = 0.f, a1 = 0.f;
#pragma unroll 4
    for (int k = 0; k < 64; ++k) {
        float wv = Ws[k * 16 + f];
        a0 = fmaf(xs[ng][k], wv, a0);
        a1 = fmaf(xs[ng + 16][k], wv, a1);
    }
    if (node0 + ng < n)      h2[(size_t)(node0 + ng) * 16 + f]      = a0 * dinv[node0 + ng];
    if (node0 + ng + 16 < n) h2[(size_t)(node0 + ng + 16) * 16 + f] = a1 * dinv[node0 + ng + 16];
}

// In-place: out[i][:] = log_softmax(out[i][:] + b2)
__global__ void k_logsoftmax(float* __restrict__ out, const float* __restrict__ b2, int n) {
    int i = blockIdx.x * blockDim.x + threadIdx.x;
    if (i >= n) return;
    const size_t base = (size_t)i * 16;
    float v[16];
#pragma unroll
    for (int f = 0; f < 16; ++f) v[f] = out[base + f] + b2[f];
    float m = v[0];
#pragma unroll
    for (int f = 1; f < 16; ++f) m = fmaxf(m, v[f]);
    float s = 0.f;
#pragma unroll
    for (int f = 0; f < 16; ++f) s += __expf(v[f] - m);
    float lse = __logf(s);
#pragma unroll
    for (int f = 0; f < 16; ++f) out[base + f] = v[f] - m - lse;
}

extern "C" void kernel_launch(void* const* d_in, const int* in_sizes, int n_in,
                              void* d_out, int out_size, void* d_ws, size_t ws_size,
                              hipStream_t stream) {
    const float* x  = (const float*)d_in[0];
    const int*   ei = (const int*)d_in[1];   // [2, E]
    const float* ew = (const float*)d_in[2];
    const float* W1 = (const float*)d_in[3];
    const float* b1 = (const float*)d_in[4];
    const float* W2 = (const float*)d_in[5];
    const float* b2 = (const float*)d_in[6];
    float* out = (float*)d_out;

    const int n = in_sizes[0] / 128;  // 100000
    const int E = in_sizes[2];        // 1600000
    const int* srcv = ei;
    const int* dstv = ei + E;
    const int nbuk = (n + BNODES - 1) >> BSHIFT;  // 782 (requires <= 1024)

    // Workspace (4B units). tmp + bucket counters alias agg1 (dead until
    // k_agg64, which runs after k_p2 retires tmp/bcnt/bcur).
    float* wsf = (float*)d_ws;
    size_t off = 0;
    float* dinv = wsf + off; off += n;
    float* h1   = wsf + off; off += (size_t)n * 64;   // reused as h2s[n*16]
    float* agg1 = wsf + off; off += (size_t)n * 64;
    off = (off + 1) & ~(size_t)1;                     // 8B align
    int2* epack = (int2*)(wsf + off); off += (size_t)E * 2;
    int* rowptr = (int*)(wsf + off); off += n + 1;
    int* boff_d = (int*)(wsf + off); off += NBUK_MAX + 1;
    int2* tmp   = (int2*)agg1;                             // [E] (12.8 MB)
    int* bcnt   = (int*)agg1 + (size_t)E * 2;              // [nbuk*CSTR]
    int* bcur   = bcnt + (size_t)nbuk * CSTR;              // [nbuk*CSTR]

    const int TB = 256;

    // --- CSR build: bucket hist -> scan -> append -> finalize(+rowptr+dinv) ---
    hipMemsetAsync(bcnt, 0, (size_t)nbuk * CSTR * sizeof(int), stream);
    k_p0<<<(E + 8191) / 8192, TB, 0, stream>>>(dstv, bcnt, E, nbuk);
    k_pscan<<<1, 1024, 0, stream>>>(bcnt, boff_d, bcur, nbuk);
    k_p1<<<(E + TB - 1) / TB, TB, 0, stream>>>(srcv, dstv, ew, bcur, tmp, E);
    k_p2<<<nbuk, TB, 0, stream>>>(tmp, boff_d, rowptr, epack, dinv, n, nbuk);

    // --- layer 1: gemm (dinv-prescaled) + gather-agg ---
    k_gemm1<<<(n + 15) / 16, TB, 0, stream>>>(x, W1, dinv, h1, n);
    k_agg64<<<(n * 64 + TB - 1) / TB, TB, 0, stream>>>(h1, rowptr, epack, dinv, agg1, n);

    // --- layer 2: gemm (+bias1+relu, dinv-prescaled) + gather-agg into d_out ---
    k_gemm2<<<(n + 31) / 32, TB, 0, stream>>>(agg1, W2, b1, dinv, h1, n);
    k_agg16<<<(n * 16 + TB - 1) / TB, TB, 0, stream>>>(h1, rowptr, epack, dinv, out, n);

    // --- epilogue ---
    k_logsoftmax<<<(n + TB - 1) / TB, TB, 0, stream>>>(out, b2, n);
}